// Round 5
// baseline (353.862 us; speedup 1.0000x reference)
//
#include <hip/hip_runtime.h>

#define B_ 2
#define N_ 28
#define D_ 128
#define H_ 8
#define DK_ 16
#define R_ (B_ * N_ * N_)   // 1568
#define GRID_ 1568
#define PROWS 4             // rows per block in phase 1
#define PUNITS 392          // 1568 / PROWS units per projection

// ---------------------------------------------------------------------------
// Single fused kernel with a software grid barrier.
// Phase 1: 4 projections, 4 rows per block (block bid: p = bid/392,
//          rows = (bid%392)*4 .. +3)  ->  ws[p][1568][128].
// Barrier: capacity-safe spin barrier (all 1568 blocks co-resident:
//          __launch_bounds__(128,4) => <=128 VGPR => >=8 blocks/CU capacity
//          = 2048 blocks > 1568).
// Phase 2: one (b,x,y) attention task per block + fused out-GEMV (R1/R4 body).
// ---------------------------------------------------------------------------
__global__ __launch_bounds__(128, 4) void edge_fused_kernel(
    const float* __restrict__ key, const float* __restrict__ value,
    const int* __restrict__ mask,
    const float* __restrict__ Wlk, const float* __restrict__ Wrk,
    const float* __restrict__ Wlv, const float* __restrict__ Wrv,
    const float* __restrict__ Wout,
    float* __restrict__ ws, unsigned* __restrict__ barrier_cnt,
    float* __restrict__ out) {
  const int tid = threadIdx.x;
  const int bid = blockIdx.x;

  __shared__ __align__(16) float xs[PROWS][D_];
  __shared__ __align__(16) float s_x[D_];

  // ---------------- phase 1: projections (4 rows per block) ----------------
  {
    const int p = bid / PUNITS;     // 0..3
    const int unit = bid % PUNITS;  // 0..391
    const float* X = (p < 2) ? key : value;
    const float* W = (p == 0) ? Wlk : (p == 1) ? Wrk : (p == 2) ? Wlv : Wrv;
    float* Y = ws + (size_t)p * R_ * D_;
    const int r0 = unit * PROWS;

#pragma unroll
    for (int i = 0; i < PROWS; ++i)
      xs[i][tid] = X[(size_t)(r0 + i) * D_ + tid];
    __syncthreads();

    const float4* w4 = reinterpret_cast<const float4*>(W + (size_t)tid * D_);
    float acc[PROWS] = {0.f, 0.f, 0.f, 0.f};
#pragma unroll
    for (int k = 0; k < D_ / 4; ++k) {
      const float4 wv = w4[k];
#pragma unroll
      for (int i = 0; i < PROWS; ++i) {
        const float4 xv = reinterpret_cast<const float4*>(xs[i])[k];
        acc[i] += xv.x * wv.x + xv.y * wv.y + xv.z * wv.z + xv.w * wv.w;
      }
    }

#pragma unroll
    for (int i = 0; i < PROWS; ++i)
      Y[(size_t)(r0 + i) * D_ + tid] = acc[i];
  }

  // ---------------- software grid barrier ----------------
  __syncthreads();
  __threadfence();  // device-scope: push phase-1 writes toward common point
  if (tid == 0) {
    // release-RMW publishes this block's writes agent-wide
    __hip_atomic_fetch_add(barrier_cnt, 1u, __ATOMIC_RELEASE,
                           __HIP_MEMORY_SCOPE_AGENT);
    while (__hip_atomic_load(barrier_cnt, __ATOMIC_ACQUIRE,
                             __HIP_MEMORY_SCOPE_AGENT) < (unsigned)GRID_) {
      __builtin_amdgcn_s_sleep(1);
    }
  }
  __syncthreads();

  // ---------------- phase 2: attention + output GEMV (task = bid) ----------
  const float* lk = ws;
  const float* rk = ws + (size_t)1 * R_ * D_;
  const float* lv = ws + (size_t)2 * R_ * D_;
  const float* rv = ws + (size_t)3 * R_ * D_;

  const int bxy = bid;          // (b*28 + x)*28 + y
  const int y = bxy % N_;
  const int bx = bxy / N_;      // b*28 + x
  const int b = bx / N_;

  const int rowL = bx * N_;          // + a      (rows of lk / lv)
  const int rowR = b * N_ * N_ + y;  // + a*N_   (rows of rk / rv)

  float s[N_];
#pragma unroll
  for (int a = 0; a < N_; ++a) {
    float pr = lk[(size_t)(rowL + a) * D_ + tid] *
               rk[(size_t)(rowR + a * N_) * D_ + tid];
    pr += __shfl_xor(pr, 1);
    pr += __shfl_xor(pr, 2);
    pr += __shfl_xor(pr, 4);
    pr += __shfl_xor(pr, 8);
    s[a] = pr * 0.25f;  // / sqrt(DK) = / 4
  }

  const int* mrow = mask + (size_t)rowL * N_ + y;  // mask[(rowL+a)*28 + y]
#pragma unroll
  for (int a = 0; a < N_; ++a)
    if (mrow[(size_t)a * N_] != 0) s[a] = -1e9f;

  float mx = -3.0e38f;
#pragma unroll
  for (int a = 0; a < N_; ++a) mx = fmaxf(mx, s[a]);
  float den = 0.f;
#pragma unroll
  for (int a = 0; a < N_; ++a) {
    s[a] = __expf(s[a] - mx);
    den += s[a];
  }
  const float inv = 1.0f / den;

  float xv = 0.f;
#pragma unroll
  for (int a = 0; a < N_; ++a) {
    xv += s[a] * lv[(size_t)(rowL + a) * D_ + tid] *
          rv[(size_t)(rowR + a * N_) * D_ + tid];
  }

  s_x[tid] = xv * inv;
  __syncthreads();

  // out[bxy][tid] = sum_k s_x[k] * Wout[tid][k]
  const float4* wrow = reinterpret_cast<const float4*>(Wout + (size_t)tid * D_);
  const float4* x4 = reinterpret_cast<const float4*>(s_x);
  float acc = 0.f;
#pragma unroll
  for (int k = 0; k < D_ / 4; ++k) {
    const float4 xk = x4[k];
    const float4 wv = wrow[k];
    acc += xk.x * wv.x + xk.y * wv.y + xk.z * wv.z + xk.w * wv.w;
  }
  out[(size_t)bxy * D_ + tid] = acc;
}

extern "C" void kernel_launch(void* const* d_in, const int* in_sizes, int n_in,
                              void* d_out, int out_size, void* d_ws,
                              size_t ws_size, hipStream_t stream) {
  // setup_inputs order:
  // 0 query (unused), 1 key, 2 value, 3 mask, 4 Wlk, 5 Wrk, 6 Wlv, 7 Wrv,
  // 8 Wq (unused), 9 Wout
  const float* key = (const float*)d_in[1];
  const float* value = (const float*)d_in[2];
  const int* mask = (const int*)d_in[3];
  const float* Wlk = (const float*)d_in[4];
  const float* Wrk = (const float*)d_in[5];
  const float* Wlv = (const float*)d_in[6];
  const float* Wrv = (const float*)d_in[7];
  const float* Wout = (const float*)d_in[9];
  float* out = (float*)d_out;
  float* ws = (float*)d_ws;

  // barrier counter lives at ws + 4 MiB (projections use first ~3.2 MiB)
  unsigned* barrier_cnt = (unsigned*)((char*)d_ws + (size_t)(4 << 20));

  hipMemsetAsync(barrier_cnt, 0, sizeof(unsigned), stream);
  edge_fused_kernel<<<dim3(GRID_), dim3(128), 0, stream>>>(
      key, value, mask, Wlk, Wrk, Wlv, Wrv, Wout, ws, barrier_cnt, out);
}

// Round 6
// 39.938 us; speedup vs baseline: 8.8603x; 8.8603x over previous
//
#include <hip/hip_runtime.h>
#include <math.h>

#define B_ 2
#define N_ 28
#define D_ 128
#define H_ 8
#define DK_ 16
#define R_ (B_ * N_ * N_)   // 1568
#define ROWS_PER_BLK 8      // 196 blocks per projection

// ---------------------------------------------------------------------------
// Kernel 1: all four projections  Y_p = X_p @ W_p^T   (unchanged from R1)
// Output layout in ws: [p][R_][128] floats.
// ---------------------------------------------------------------------------
__global__ __launch_bounds__(128) void proj4_kernel(
    const float* __restrict__ key, const float* __restrict__ value,
    const float* __restrict__ Wlk, const float* __restrict__ Wrk,
    const float* __restrict__ Wlv, const float* __restrict__ Wrv,
    float* __restrict__ ws) {
  const int p = blockIdx.y;
  const float* X = (p < 2) ? key : value;
  const float* W = (p == 0) ? Wlk : (p == 1) ? Wrk : (p == 2) ? Wlv : Wrv;
  float* Y = ws + (size_t)p * R_ * D_;

  const int r0 = blockIdx.x * ROWS_PER_BLK;
  const int c = threadIdx.x;

  __shared__ __align__(16) float xs[ROWS_PER_BLK][D_];
#pragma unroll
  for (int i = 0; i < ROWS_PER_BLK; ++i)
    xs[i][c] = X[(size_t)(r0 + i) * D_ + c];
  __syncthreads();

  const float4* w4 = reinterpret_cast<const float4*>(W + (size_t)c * D_);
  float acc[ROWS_PER_BLK];
#pragma unroll
  for (int i = 0; i < ROWS_PER_BLK; ++i) acc[i] = 0.f;

#pragma unroll
  for (int k = 0; k < D_ / 4; ++k) {
    const float4 wv = w4[k];
#pragma unroll
    for (int i = 0; i < ROWS_PER_BLK; ++i) {
      const float4 xv = reinterpret_cast<const float4*>(xs[i])[k];
      acc[i] += xv.x * wv.x + xv.y * wv.y + xv.z * wv.z + xv.w * wv.w;
    }
  }

#pragma unroll
  for (int i = 0; i < ROWS_PER_BLK; ++i)
    Y[(size_t)(r0 + i) * D_ + c] = acc[i];
}

// ---------------------------------------------------------------------------
// Kernel 2 (rewritten): block = one (b,x,y) task, 256 threads.
//   h = tid>>5 (0..7), a = tid&31 (0..27 active, 28..31 idle).
//   QK: per-thread dot-16 (4x float4 per operand, all in one cache line).
//   softmax over a: 5-level shfl_xor within the 32-lane a-group.
//   PV: per-thread 16 products, butterfly-reduced over the a-group.
//   Result x_row staged in LDS, written coalesced by threads 0..127.
// ---------------------------------------------------------------------------
__global__ __launch_bounds__(256) void attn_kernel(
    const float* __restrict__ ws, const int* __restrict__ mask,
    float* __restrict__ xout) {
  const float* lk = ws;
  const float* rk = ws + (size_t)1 * R_ * D_;
  const float* lv = ws + (size_t)2 * R_ * D_;
  const float* rv = ws + (size_t)3 * R_ * D_;

  const int bxy = blockIdx.x;   // (b*28 + x)*28 + y
  const int y = bxy % N_;
  const int bx = bxy / N_;      // b*28 + x
  const int b = bx / N_;

  const int tid = threadIdx.x;
  const int h = tid >> 5;       // head 0..7
  const int a = tid & 31;       // intermediate node 0..31 (28 active)
  const bool act = (a < N_);
  const int al = act ? a : (N_ - 1);  // clamp idle lanes to a valid row

  const int rowL = bx * N_;          // + a      (rows of lk / lv)
  const int rowR = b * N_ * N_ + y;  // + a*N_   (rows of rk / rv)

  // ---- QK: s = <lk[rowL+a, h*16:], rk[rowR+a*28, h*16:]> / 4 ----
  const float4* lk4 =
      reinterpret_cast<const float4*>(lk + (size_t)(rowL + al) * D_ + h * DK_);
  const float4* rk4 = reinterpret_cast<const float4*>(
      rk + (size_t)(rowR + al * N_) * D_ + h * DK_);
  float s = 0.f;
#pragma unroll
  for (int j = 0; j < 4; ++j) {
    const float4 u = lk4[j];
    const float4 v = rk4[j];
    s += u.x * v.x + u.y * v.y + u.z * v.z + u.w * v.w;
  }
  s *= 0.25f;  // / sqrt(DK)

  if (act && mask[(size_t)(rowL + a) * N_ + y] != 0) s = -1e9f;
  if (!act) s = -INFINITY;  // idle lanes vanish from softmax

  // ---- softmax over the 32-lane a-group (masks 1..16 stay in-group) ----
  float mx = s;
#pragma unroll
  for (int m = 1; m <= 16; m <<= 1) mx = fmaxf(mx, __shfl_xor(mx, m));
  float e = __expf(s - mx);  // -INF -> 0
  float den = e;
#pragma unroll
  for (int m = 1; m <= 16; m <<= 1) den += __shfl_xor(den, m);
  const float att = e / den;

  // ---- PV: acc[j] = sum_a att * lv * rv  (16 floats per (h)) ----
  const float4* lv4 =
      reinterpret_cast<const float4*>(lv + (size_t)(rowL + al) * D_ + h * DK_);
  const float4* rv4 = reinterpret_cast<const float4*>(
      rv + (size_t)(rowR + al * N_) * D_ + h * DK_);
  float4 acc[4];
#pragma unroll
  for (int j = 0; j < 4; ++j) {
    const float4 u = lv4[j];
    const float4 v = rv4[j];
    acc[j].x = att * u.x * v.x;
    acc[j].y = att * u.y * v.y;
    acc[j].z = att * u.z * v.z;
    acc[j].w = att * u.w * v.w;
  }
#pragma unroll
  for (int m = 1; m <= 16; m <<= 1) {
#pragma unroll
    for (int j = 0; j < 4; ++j) {
      acc[j].x += __shfl_xor(acc[j].x, m);
      acc[j].y += __shfl_xor(acc[j].y, m);
      acc[j].z += __shfl_xor(acc[j].z, m);
      acc[j].w += __shfl_xor(acc[j].w, m);
    }
  }

  __shared__ __align__(16) float s_x[D_];
  if (a == 0) {
    float4* dst = reinterpret_cast<float4*>(s_x + h * DK_);
#pragma unroll
    for (int j = 0; j < 4; ++j) dst[j] = acc[j];
  }
  __syncthreads();

  if (tid < D_) xout[(size_t)bxy * D_ + tid] = s_x[tid];
}

// ---------------------------------------------------------------------------
// Kernel 3: out = x @ Wout^T   (unchanged from R1)
// ---------------------------------------------------------------------------
__global__ __launch_bounds__(128) void gemm_out_kernel(
    const float* __restrict__ X, const float* __restrict__ W,
    float* __restrict__ Y) {
  const int r0 = blockIdx.x * ROWS_PER_BLK;
  const int c = threadIdx.x;

  __shared__ __align__(16) float xs[ROWS_PER_BLK][D_];
#pragma unroll
  for (int i = 0; i < ROWS_PER_BLK; ++i)
    xs[i][c] = X[(size_t)(r0 + i) * D_ + c];
  __syncthreads();

  const float4* w4 = reinterpret_cast<const float4*>(W + (size_t)c * D_);
  float acc[ROWS_PER_BLK];
#pragma unroll
  for (int i = 0; i < ROWS_PER_BLK; ++i) acc[i] = 0.f;

#pragma unroll
  for (int k = 0; k < D_ / 4; ++k) {
    const float4 wv = w4[k];
#pragma unroll
    for (int i = 0; i < ROWS_PER_BLK; ++i) {
      const float4 xv = reinterpret_cast<const float4*>(xs[i])[k];
      acc[i] += xv.x * wv.x + xv.y * wv.y + xv.z * wv.z + xv.w * wv.w;
    }
  }

#pragma unroll
  for (int i = 0; i < ROWS_PER_BLK; ++i)
    Y[(size_t)(r0 + i) * D_ + c] = acc[i];
}

extern "C" void kernel_launch(void* const* d_in, const int* in_sizes, int n_in,
                              void* d_out, int out_size, void* d_ws,
                              size_t ws_size, hipStream_t stream) {
  // 0 query (unused), 1 key, 2 value, 3 mask, 4 Wlk, 5 Wrk, 6 Wlv, 7 Wrv,
  // 8 Wq (unused), 9 Wout
  const float* key = (const float*)d_in[1];
  const float* value = (const float*)d_in[2];
  const int* mask = (const int*)d_in[3];
  const float* Wlk = (const float*)d_in[4];
  const float* Wrk = (const float*)d_in[5];
  const float* Wlv = (const float*)d_in[6];
  const float* Wrv = (const float*)d_in[7];
  const float* Wout = (const float*)d_in[9];
  float* out = (float*)d_out;
  float* ws = (float*)d_ws;
  float* xbuf = ws + (size_t)4 * R_ * D_;  // pre-Wout x, [1568][128]

  proj4_kernel<<<dim3(R_ / ROWS_PER_BLK, 4), 128, 0, stream>>>(
      key, value, Wlk, Wrk, Wlv, Wrv, ws);
  attn_kernel<<<dim3(R_), 256, 0, stream>>>(ws, mask, xbuf);
  gemm_out_kernel<<<dim3(R_ / ROWS_PER_BLK), 128, 0, stream>>>(xbuf, Wout, out);
}